// Round 5
// baseline (197.837 us; speedup 1.0000x reference)
//
#include <hip/hip_runtime.h>
#include <float.h>

#define K_CODES 1024
#define DIM 64
#define T_LEN 8192
#define N_TOK 131072          // 16 * 8192 tokens
#define LO_SCALE 2048.0f
#define LO_INV   (1.0f / 2048.0f)

typedef _Float16 half8  __attribute__((ext_vector_type(8)));  // 4 VGPRs: MFMA A/B frag
typedef _Float16 half2v __attribute__((ext_vector_type(2)));  // 1 VGPR: packed pair
typedef __fp16   fp16x2 __attribute__((ext_vector_type(2)));  // cvt_pkrtz native type
typedef float    f32x4  __attribute__((ext_vector_type(4)));  // MFMA C/D frag

union H8 { half8 v; half2v p[4]; };

// Truncation split: hi = x with mantissa truncated to 11 bits (exactly f16-representable,
// so pkrtz is exact); lo = (x - hi) * 2048 (pkrtz, residual <= 2^-20 |x|).
// f16-denormal hi (|x| < 6e-5): pkrtz rounds, absolute error < 6e-8 — negligible.
__device__ inline void split2(float x0, float x1, half2v& h, half2v& l) {
    float h0 = __uint_as_float(__float_as_uint(x0) & 0xFFFFE000u);
    float h1 = __uint_as_float(__float_as_uint(x1) & 0xFFFFE000u);
    h = __builtin_bit_cast(half2v, __builtin_amdgcn_cvt_pkrtz(h0, h1));
    l = __builtin_bit_cast(half2v, __builtin_amdgcn_cvt_pkrtz((x0 - h0) * LO_SCALE,
                                                              (x1 - h1) * LO_SCALE));
}

// Single fused kernel: split-f16 GEMM + argmin + gather. No prep, no d_ws
// (rounds 2/3 carried a constant ~62 us tied to the 2-kernel+ws structure).
// Wave = 32 tokens (2 m-tiles), all 1024 codes -> 4096 waves = 4/SIMD (2x round-3 TLP).
__global__ __launch_bounds__(256, 4)
void vq_fused(const float* __restrict__ in,
              const float* __restrict__ cb,
              float* __restrict__ out) {
    __shared__ int idx_s[128];

    const int tid  = threadIdx.x;
    const int wave = tid >> 6;
    const int lane = tid & 63;
    const int lo4  = lane & 15;   // code residue (C col) / token residue (A m)
    const int quad = lane >> 4;   // k-offset selector in A/B frags; token-row group in C

    const int strip = blockIdx.x * 128 + wave * 32;   // 32 tokens per wave
    const int b  = strip >> 13;
    const int t0 = strip & 8191;

    // ---- A fragments: -2 * X[token][d] -> f16 hi/lo (RN split, one-time) ----
    // A layout (16x16x32, HW-verified rounds 2/3): m = lane&15, k = quad*8 + j (+ s*32)
    const float* xin = in + (size_t)b * DIM * T_LEN + t0;
    half8 a_hi[2][2], a_lo[2][2];
    #pragma unroll
    for (int mt = 0; mt < 2; ++mt) {
        #pragma unroll
        for (int s = 0; s < 2; ++s) {
            H8 hh, ll;
            #pragma unroll
            for (int jp = 0; jp < 4; ++jp) {
                const int d0 = s * 32 + quad * 8 + jp * 2;
                float x0 = -2.0f * xin[(size_t)(d0 + 0) * T_LEN + mt * 16 + lo4];
                float x1 = -2.0f * xin[(size_t)(d0 + 1) * T_LEN + mt * 16 + lo4];
                _Float16 h0 = (_Float16)x0, h1 = (_Float16)x1;
                half2v hp, lp;
                hp[0] = h0; hp[1] = h1;
                lp[0] = (_Float16)((x0 - (float)h0) * LO_SCALE);
                lp[1] = (_Float16)((x1 - (float)h1) * LO_SCALE);
                hh.p[jp] = hp; ll.p[jp] = lp;
            }
            a_hi[mt][s] = hh.v;
            a_lo[mt][s] = ll.v;
        }
    }

    // ---- running argmin: slot i = mt*4 + r -> token strip + mt*16 + quad*4 + r ----
    float best[8];
    int   bidx[8];
    #pragma unroll
    for (int i = 0; i < 8; ++i) { best[i] = FLT_MAX; bidx[i] = 0; }

    // B tile: code = ct*16 + lo4, dims quad*8.. (+4) and +32.. (+36), fp32 from L2/L3.
    const float* bbase = cb + (size_t)lo4 * DIM + quad * 8;

    for (int ct = 0; ct < 64; ++ct) {
        const float* bp = bbase + (size_t)ct * 16 * DIM;
        float4 f0 = *reinterpret_cast<const float4*>(bp);
        float4 f1 = *reinterpret_cast<const float4*>(bp + 4);
        float4 f2 = *reinterpret_cast<const float4*>(bp + 32);
        float4 f3 = *reinterpret_cast<const float4*>(bp + 36);

        // e_sq for code ct*16+lo4: per-lane partial over 16 dims, reduce across quads.
        float p0 = fmaf(f0.x, f0.x, fmaf(f0.y, f0.y, fmaf(f0.z, f0.z, f0.w * f0.w)));
        float p1 = fmaf(f1.x, f1.x, fmaf(f1.y, f1.y, fmaf(f1.z, f1.z, f1.w * f1.w)));
        float p2 = fmaf(f2.x, f2.x, fmaf(f2.y, f2.y, fmaf(f2.z, f2.z, f2.w * f2.w)));
        float p3 = fmaf(f3.x, f3.x, fmaf(f3.y, f3.y, fmaf(f3.z, f3.z, f3.w * f3.w)));
        float pe = (p0 + p1) + (p2 + p3);
        pe += __shfl_xor(pe, 16, 64);
        pe += __shfl_xor(pe, 32, 64);   // all 4 quads summed -> full ||e||^2

        // on-the-fly f16 hi/lo split of the B tile (packed)
        H8 bh0, bl0, bh1, bl1;
        split2(f0.x, f0.y, bh0.p[0], bl0.p[0]);
        split2(f0.z, f0.w, bh0.p[1], bl0.p[1]);
        split2(f1.x, f1.y, bh0.p[2], bl0.p[2]);
        split2(f1.z, f1.w, bh0.p[3], bl0.p[3]);
        split2(f2.x, f2.y, bh1.p[0], bl1.p[0]);
        split2(f2.z, f2.w, bh1.p[1], bl1.p[1]);
        split2(f3.x, f3.y, bh1.p[2], bl1.p[2]);
        split2(f3.z, f3.w, bh1.p[3], bl1.p[3]);

        const int code = ct * 16 + lo4;
        #pragma unroll
        for (int mt = 0; mt < 2; ++mt) {
            f32x4 c1 = {pe, pe, pe, pe};    // ||e||^2 folded into C input
            f32x4 c2 = {0.f, 0.f, 0.f, 0.f};
            c1 = __builtin_amdgcn_mfma_f32_16x16x32_f16(a_hi[mt][0], bh0.v, c1, 0, 0, 0);
            c1 = __builtin_amdgcn_mfma_f32_16x16x32_f16(a_hi[mt][1], bh1.v, c1, 0, 0, 0);
            c2 = __builtin_amdgcn_mfma_f32_16x16x32_f16(a_lo[mt][0], bh0.v, c2, 0, 0, 0);
            c2 = __builtin_amdgcn_mfma_f32_16x16x32_f16(a_lo[mt][1], bh1.v, c2, 0, 0, 0);
            c2 = __builtin_amdgcn_mfma_f32_16x16x32_f16(a_hi[mt][0], bl0.v, c2, 0, 0, 0);
            c2 = __builtin_amdgcn_mfma_f32_16x16x32_f16(a_hi[mt][1], bl1.v, c2, 0, 0, 0);
            #pragma unroll
            for (int r = 0; r < 4; ++r) {
                float sc = fmaf(c2[r], LO_INV, c1[r]);  // ||e||^2 - 2 x.e
                const int i = mt * 4 + r;
                bool lt = sc < best[i];                  // strict <: first occurrence wins
                best[i] = lt ? sc : best[i];
                bidx[i] = lt ? code : bidx[i];
            }
        }
    }

    // ---- cross-lane merge over the 16 code-residue lanes ----
    #pragma unroll
    for (int i = 0; i < 8; ++i) {
        float s = best[i];
        int  ix = bidx[i];
        #pragma unroll
        for (int off = 1; off < 16; off <<= 1) {
            float s2 = __shfl_xor(s, off, 64);
            int  ix2 = __shfl_xor(ix, off, 64);
            bool take = (s2 < s) || (s2 == s && ix2 < ix);  // tie -> lower index
            s  = take ? s2 : s;
            ix = take ? ix2 : ix;
        }
        if (lo4 == 0) {
            // token_local = mt*16 + quad*4 + r,  mt = i>>2, r = i&3
            idx_s[wave * 32 + (i >> 2) * 16 + quad * 4 + (i & 3)] = ix;
        }
    }
    __syncthreads();

    // ---- epilogue: 2 threads per token (32 dims each), gather + coalesced store ----
    const int tok_local = tid & 127;               // block covers 128 contiguous tokens
    const int dhalf = tid >> 7;                    // 0: dims 0..31, 1: dims 32..63
    const int token = blockIdx.x * 128 + tok_local;
    const int tb = token >> 13;
    const int tt = token & 8191;
    const int my_idx = idx_s[tok_local];

    if (dhalf == 0)
        out[(size_t)N_TOK * DIM + token] = (float)my_idx;   // index output

    const float* crow = cb + (size_t)my_idx * DIM + dhalf * 32;
    float* outv = out + (size_t)tb * DIM * T_LEN + (size_t)(dhalf * 32) * T_LEN + tt;
    #pragma unroll
    for (int d0 = 0; d0 < 32; d0 += 4) {
        float4 v = *reinterpret_cast<const float4*>(crow + d0);  // L2-hot gather
        outv[(size_t)(d0 + 0) * T_LEN] = v.x;
        outv[(size_t)(d0 + 1) * T_LEN] = v.y;
        outv[(size_t)(d0 + 2) * T_LEN] = v.z;
        outv[(size_t)(d0 + 3) * T_LEN] = v.w;
    }
}

extern "C" void kernel_launch(void* const* d_in, const int* in_sizes, int n_in,
                              void* d_out, int out_size, void* d_ws, size_t ws_size,
                              hipStream_t stream) {
    const float* in = (const float*)d_in[0];   // (16, 64, 8192) fp32
    const float* cb = (const float*)d_in[1];   // (1024, 64) fp32
    float* out = (float*)d_out;

    vq_fused<<<dim3(N_TOK / 128), dim3(256), 0, stream>>>(in, cb, out);
}

// Round 6
// 134.027 us; speedup vs baseline: 1.4761x; 1.4761x over previous
//
#include <hip/hip_runtime.h>
#include <float.h>

#define K_CODES 1024
#define DIM 64
#define T_LEN 8192
#define N_TOK 131072          // 16 * 8192 tokens
#define LO_SCALE 2048.0f
#define LO_INV   (1.0f / 2048.0f)

typedef _Float16 half8 __attribute__((ext_vector_type(8)));  // 4 VGPRs: MFMA A/B frag
typedef float    f32x4 __attribute__((ext_vector_type(4)));  // MFMA C/D frag

#define MFMA16(a, b, c) __builtin_amdgcn_mfma_f32_16x16x32_f16((a), (b), (c), 0, 0, 0)

// ---------------- prep: codebook -> tiled f16 hi/lo + e_sq ----------------
// Tile ct (16 codes) = 2048 f16 (4 KB), contiguous, in frag order:
//   hi: [q=0..7][code=0..15][j=0..7] (k = q*8+j), then lo same order at +1024.
// A wave in vq_main reads the whole tile with 4 coalesced 16B/lane loads.
// One block per tile: 64 blocks x 256 threads; 16B coalesced stores.
__global__ void vq_prep(const float* __restrict__ cb,
                        _Float16* __restrict__ w,
                        float* __restrict__ wesq) {
    __shared__ float part[128];
    const int ct   = blockIdx.x;
    const int r    = threadIdx.x;
    const int halF = r >> 7;           // 0: hi chunk, 1: lo chunk
    const int rr   = r & 127;
    const int q    = rr >> 4;          // k-octet
    const int code = rr & 15;

    const float* src = cb + (size_t)(ct * 16 + code) * DIM + q * 8;
    float4 v0 = *reinterpret_cast<const float4*>(src);
    float4 v1 = *reinterpret_cast<const float4*>(src + 4);
    float x[8] = {v0.x, v0.y, v0.z, v0.w, v1.x, v1.y, v1.z, v1.w};

    half8 o;
    float psum = 0.0f;
    #pragma unroll
    for (int j = 0; j < 8; ++j) {
        _Float16 h = (_Float16)x[j];
        o[j] = halF ? (_Float16)((x[j] - (float)h) * LO_SCALE) : h;  // (x-h) exact in fp32
        psum = fmaf(x[j], x[j], psum);
    }
    *reinterpret_cast<half8*>(w + (size_t)ct * 2048 + halF * 1024 + q * 128 + code * 8) = o;

    if (halF == 0) part[rr] = psum;
    __syncthreads();
    if (r < 16) {
        float s = 0.0f;
        #pragma unroll
        for (int q2 = 0; q2 < 8; ++q2) s += part[q2 * 16 + r];
        wesq[ct * 16 + r] = s;
    }
}

// ---------------- main: split-f16 MFMA + fused argmin + gather ----------------
// Wave = 32 tokens (2 m-tiles). 4096 waves = 4 waves/SIMD (vs round 3's 2).
// Loop body: 4 coalesced B loads + 1 esq load (ping-pong prefetch, no barriers ->
// loads stay in flight across iterations), 12 MFMA, ~40 VALU argmin.
__global__ __launch_bounds__(256, 4)
void vq_main(const float* __restrict__ in,
             const float* __restrict__ cb,
             const _Float16* __restrict__ w,
             const float* __restrict__ wesq,
             float* __restrict__ out) {
    __shared__ int idx_s[128];

    const int tid  = threadIdx.x;
    const int wave = tid >> 6;
    const int lane = tid & 63;
    const int lo4  = lane & 15;   // code residue (C col) / token residue (A m)
    const int quad = lane >> 4;   // k-octet selector in A/B frags; token-row group in C

    const int strip = blockIdx.x * 128 + wave * 32;   // 32 tokens per wave
    const int b  = strip >> 13;
    const int t0 = strip & 8191;

    // ---- A fragments: -2 * X[token][d] -> f16 hi/lo (layout HW-verified r2-r5) ----
    const float* xin = in + (size_t)b * DIM * T_LEN + t0;
    half8 a_hi[2][2], a_lo[2][2];
    #pragma unroll
    for (int mt = 0; mt < 2; ++mt) {
        #pragma unroll
        for (int s = 0; s < 2; ++s) {
            half8 hh, ll;
            #pragma unroll
            for (int j = 0; j < 8; ++j) {
                const int d = s * 32 + quad * 8 + j;
                float xv = -2.0f * xin[(size_t)d * T_LEN + mt * 16 + lo4];
                _Float16 h = (_Float16)xv;
                hh[j] = h;
                ll[j] = (_Float16)((xv - (float)h) * LO_SCALE);
            }
            a_hi[mt][s] = hh;
            a_lo[mt][s] = ll;
        }
    }

    float best[8];
    int   bidx[8];
    #pragma unroll
    for (int i = 0; i < 8; ++i) { best[i] = FLT_MAX; bidx[i] = 0; }

    // B tile reads: lane's 4 frags sit at tile + {0,512,1024,1536} + lane*8 (f16 elems)
    // -> four perfectly coalesced dwordx4 loads per wave per tile.
    const _Float16* wb = w + (size_t)lane * 8;

    half8 Ah0, Ah1, Al0, Al1, Bh0, Bh1, Bl0, Bl1;
    float Ae, Be;

    auto loadB = [&](int ct, half8& h0, half8& h1, half8& l0, half8& l1, float& es) {
        const _Float16* p = wb + (size_t)ct * 2048;
        h0 = *reinterpret_cast<const half8*>(p);          // hi, k 0..31  (q=quad)
        h1 = *reinterpret_cast<const half8*>(p + 512);    // hi, k 32..63 (q=4+quad)
        l0 = *reinterpret_cast<const half8*>(p + 1024);   // lo, k 0..31
        l1 = *reinterpret_cast<const half8*>(p + 1536);   // lo, k 32..63
        es = wesq[ct * 16 + lo4];
    };
    auto step = [&](const half8& h0, const half8& h1, const half8& l0,
                    const half8& l1, float es, int ct) {
        const int code = ct * 16 + lo4;
        #pragma unroll
        for (int mt = 0; mt < 2; ++mt) {
            f32x4 c1 = {es, es, es, es};    // ||e||^2 folded into C input
            f32x4 c2 = {0.f, 0.f, 0.f, 0.f};
            c1 = MFMA16(a_hi[mt][0], h0, c1);
            c1 = MFMA16(a_hi[mt][1], h1, c1);
            c2 = MFMA16(a_lo[mt][0], h0, c2);
            c2 = MFMA16(a_lo[mt][1], h1, c2);
            c2 = MFMA16(a_hi[mt][0], l0, c2);
            c2 = MFMA16(a_hi[mt][1], l1, c2);
            #pragma unroll
            for (int r = 0; r < 4; ++r) {
                float sc = fmaf(c2[r], LO_INV, c1[r]);  // ||e||^2 - 2 x.e
                const int i = mt * 4 + r;
                bool lt = sc < best[i];                  // strict <: first occurrence wins
                best[i] = lt ? sc : best[i];
                bidx[i] = lt ? code : bidx[i];
            }
        }
    };

    // ping-pong: while computing tile ct, tile ct+1's loads are in flight
    loadB(0, Ah0, Ah1, Al0, Al1, Ae);
    loadB(1, Bh0, Bh1, Bl0, Bl1, Be);
    for (int p = 0; p < 31; ++p) {
        step(Ah0, Ah1, Al0, Al1, Ae, 2 * p);
        loadB(2 * p + 2, Ah0, Ah1, Al0, Al1, Ae);
        step(Bh0, Bh1, Bl0, Bl1, Be, 2 * p + 1);
        loadB(2 * p + 3, Bh0, Bh1, Bl0, Bl1, Be);
    }
    step(Ah0, Ah1, Al0, Al1, Ae, 62);
    step(Bh0, Bh1, Bl0, Bl1, Be, 63);

    // ---- cross-lane merge over the 16 code-residue lanes ----
    #pragma unroll
    for (int i = 0; i < 8; ++i) {
        float s = best[i];
        int  ix = bidx[i];
        #pragma unroll
        for (int off = 1; off < 16; off <<= 1) {
            float s2 = __shfl_xor(s, off, 64);
            int  ix2 = __shfl_xor(ix, off, 64);
            bool take = (s2 < s) || (s2 == s && ix2 < ix);  // tie -> lower index
            s  = take ? s2 : s;
            ix = take ? ix2 : ix;
        }
        if (lo4 == 0) {
            // token_local = mt*16 + quad*4 + r,  mt = i>>2, r = i&3
            idx_s[wave * 32 + (i >> 2) * 16 + quad * 4 + (i & 3)] = ix;
        }
    }
    __syncthreads();

    // ---- epilogue: 2 threads per token (32 dims each), gather + coalesced store ----
    const int tok_local = tid & 127;
    const int dhalf = tid >> 7;
    const int token = blockIdx.x * 128 + tok_local;
    const int tb = token >> 13;
    const int tt = token & 8191;
    const int my_idx = idx_s[tok_local];

    if (dhalf == 0)
        out[(size_t)N_TOK * DIM + token] = (float)my_idx;   // index output

    const float* crow = cb + (size_t)my_idx * DIM + dhalf * 32;
    float* outv = out + (size_t)tb * DIM * T_LEN + (size_t)(dhalf * 32) * T_LEN + tt;
    #pragma unroll
    for (int d0 = 0; d0 < 32; d0 += 4) {
        float4 v = *reinterpret_cast<const float4*>(crow + d0);  // L2-hot gather
        outv[(size_t)(d0 + 0) * T_LEN] = v.x;
        outv[(size_t)(d0 + 1) * T_LEN] = v.y;
        outv[(size_t)(d0 + 2) * T_LEN] = v.z;
        outv[(size_t)(d0 + 3) * T_LEN] = v.w;
    }
}

extern "C" void kernel_launch(void* const* d_in, const int* in_sizes, int n_in,
                              void* d_out, int out_size, void* d_ws, size_t ws_size,
                              hipStream_t stream) {
    const float* in = (const float*)d_in[0];   // (16, 64, 8192) fp32
    const float* cb = (const float*)d_in[1];   // (1024, 64) fp32
    float* out = (float*)d_out;

    _Float16* w   = (_Float16*)d_ws;                       // 64 tiles * 4 KB = 256 KB
    float*   wesq = (float*)((char*)d_ws + 64 * 4096);     // 4 KB

    vq_prep<<<dim3(64), dim3(256), 0, stream>>>(cb, w, wesq);
    vq_main<<<dim3(N_TOK / 128), dim3(256), 0, stream>>>(in, cb, w, wesq, out);
}